// Round 1
// baseline (213.894 us; speedup 1.0000x reference)
//
#include <hip/hip_runtime.h>

#define N   2048
#define NT  256
#define EPK 8   // elements per thread (N/NT)

// monotone float->uint key: ascending uint order == ascending float order
__device__ __forceinline__ unsigned int fkey(float f) {
  unsigned int u = __float_as_uint(f);
  return (u & 0x80000000u) ? ~u : (u | 0x80000000u);
}

__global__ __launch_bounds__(NT) void listmle_kernel(
    const float* __restrict__ input1,
    const float* __restrict__ input2,
    const int*  __restrict__ mask2,
    float* __restrict__ out) {
  __shared__ unsigned long long arr[N];   // 16 KB: sort keys (value<<32 | payload)
  __shared__ unsigned int pay[N];         // 8 KB: compacted sorted payloads
  __shared__ float row[N];                // 8 KB: staged input1 row for current channel
  __shared__ float wscan[NT / 64];
  __shared__ float wprod[NT / 64];

  const int p   = blockIdx.x;             // p = b*32 + h
  const int tid = threadIdx.x;
  const long long base2 = (long long)p * N;

  // ---- build keys (coalesced loads) ----
  for (int k = 0; k < EPK; ++k) {
    int i = tid + NT * k;
    float v = input2[base2 + i];
    int   m = mask2[base2 + i];
    unsigned int kk = fkey((m > 0) ? v : 100000.0f);
    // payload: keep-bit at 16 dominates ties -> reproduces stable argsort order
    unsigned int pl = (unsigned int)i | ((m > 0) ? 0x10000u : 0u);
    arr[i] = ((unsigned long long)kk << 32) | pl;
  }

  // ---- bitonic sort ascending (66 passes) ----
  for (int k = 2; k <= N; k <<= 1) {
    for (int j = k >> 1; j >= 1; j >>= 1) {
      __syncthreads();
      for (int t = tid; t < N / 2; t += NT) {
        int i   = ((t & ~(j - 1)) << 1) | (t & (j - 1));
        int ixj = i | j;
        unsigned long long a = arr[i], b = arr[ixj];
        bool up = ((i & k) == 0);
        if ((a > b) == up) { arr[i] = b; arr[ixj] = a; }
      }
    }
  }
  __syncthreads();

  // ---- compact payloads to u32 array ----
  for (int k = 0; k < EPK; ++k) {
    int i = tid + NT * k;
    pay[i] = (unsigned int)(arr[i] & 0xFFFFFFFFu);
  }
  __syncthreads();

  // each thread owns 8 consecutive sorted positions; read payloads once,
  // reuse across the 4 channels
  unsigned int pl[EPK];
  for (int k = 0; k < EPK; ++k) pl[k] = pay[tid * EPK + k];

  const int lane = tid & 63;
  const int wv   = tid >> 6;
  const int b    = p >> 5, h = p & 31;

  for (int c = 0; c < 4; ++c) {
    const float* r1 = input1 + ((long long)((b * 4 + c) * 32 + h)) * N;
    __syncthreads();                       // protect row[] reuse across channels
    for (int k = 0; k < EPK; ++k) {
      int i = tid + NT * k;
      row[i] = r1[i];                      // coalesced global -> LDS
    }
    __syncthreads();

    // gather + exp; thread-local sum of its 8 sorted elements
    float e[EPK];
    float lsum = 0.f;
    for (int k = 0; k < EPK; ++k) {
      unsigned int q = pl[k];
      float v  = row[q & 0xFFFFu];
      float pe = (q & 0x10000u) ? __expf(v) : 0.f;
      e[k] = pe;
      lsum += pe;
    }

    // block exclusive scan of per-thread sums
    float inc = lsum;
    for (int d = 1; d < 64; d <<= 1) {
      float o = __shfl_up(inc, d, 64);
      if (lane >= d) inc += o;
    }
    if (lane == 63) wscan[wv] = inc;
    __syncthreads();
    float woff = 0.f;
    for (int w = 0; w < wv; ++w) woff += wscan[w];
    float excl = woff + inc - lsum;        // exclusive prefix for this thread

    // factors + local product; masked entries contribute exactly 1
    float prod = 1.f;
    float cum  = excl;
    for (int k = 0; k < EPK; ++k) {
      cum += e[k];
      if (pl[k] & 0x10000u) {
        prod *= (e[k] + 1e-9f) / (cum + 1e-9f);
      }
    }

    // block product reduction
    for (int d = 32; d >= 1; d >>= 1) prod *= __shfl_xor(prod, d, 64);
    if (lane == 0) wprod[wv] = prod;
    __syncthreads();
    if (tid == 0) {
      out[p * 4 + c] = wprod[0] * wprod[1] * wprod[2] * wprod[3];
    }
  }
}

extern "C" void kernel_launch(void* const* d_in, const int* in_sizes, int n_in,
                              void* d_out, int out_size, void* d_ws, size_t ws_size,
                              hipStream_t stream) {
  const float* input1 = (const float*)d_in[0];
  // d_in[1] = mask1 — unused by the reference forward
  const float* input2 = (const float*)d_in[2];
  const int*   mask2  = (const int*)d_in[3];
  float* out = (float*)d_out;

  const int problems = 128 * 32;  // bs * nh
  listmle_kernel<<<problems, NT, 0, stream>>>(input1, input2, mask2, out);
}

// Round 2
// 142.667 us; speedup vs baseline: 1.4993x; 1.4993x over previous
//
#include <hip/hip_runtime.h>

#define N   2048
#define NT  256
#define EPK 8   // elements per thread (N/NT)

typedef unsigned long long u64;
typedef unsigned int u32;

// monotone float->uint key: ascending uint order == ascending float order
__device__ __forceinline__ u32 fkey(float f) {
  u32 u = __float_as_uint(f);
  return (u & 0x80000000u) ? ~u : (u | 0x80000000u);
}

// XOR-linear bijective LDS slot swizzle. Derivation: u64 element e sits at
// byte 8*s(e); bank half = slot bit3, 16B-quad-in-row = slot bits [3:1].
//   bit3 ^= e4 ^ e6, bits[3:1] ^= e[6:4]  ->
//   j=8 bitonic pass (i bit3==0) spreads across both bank halves, and the
//   b128 roundtrip (lane stride 64B) hits all 8 quads per row.
// Linear over GF(2): s(i^j) = s(i)^s(j), bit0 untouched (u64 pairs stay
// contiguous and 16B-aligned for b128).
__device__ __forceinline__ int sw(int e) {
  return e ^ ((e >> 3) & 0xE) ^ ((e >> 1) & 8);
}

#define CE(x, y, up)                                  \
  {                                                   \
    if ((kv[x] > kv[y]) == (up)) {                    \
      u64 t_ = kv[x]; kv[x] = kv[y]; kv[y] = t_;      \
    }                                                 \
  }

__global__ __launch_bounds__(NT, 6) void listmle_kernel(
    const float* __restrict__ input1,
    const float* __restrict__ input2,
    const int* __restrict__ mask2,
    float* __restrict__ out) {
  __shared__ __align__(16) u64 arr[N];  // 16 KB; reused as 2 float rows in channel phase
  __shared__ float wscan[NT / 64];
  __shared__ float wprod[NT / 64];

  const int p = blockIdx.x;        // p = b*32 + h
  const int tid = threadIdx.x;
  const int gbase = tid * EPK;     // this thread's 8 consecutive element slots
  const long long base2 = (long long)p * N;

  // ---- load 8 consecutive elements (32B/lane contiguous), build sort items ----
  const float4* i2v = (const float4*)(input2 + base2);
  const int4* m2v = (const int4*)(mask2 + base2);
  float4 va = i2v[2 * tid], vb = i2v[2 * tid + 1];
  int4 ma = m2v[2 * tid], mb = m2v[2 * tid + 1];

  u64 kv[EPK];
  {
    float vv[EPK] = {va.x, va.y, va.z, va.w, vb.x, vb.y, vb.z, vb.w};
    int mm[EPK] = {ma.x, ma.y, ma.z, ma.w, mb.x, mb.y, mb.z, mb.w};
#pragma unroll
    for (int m = 0; m < EPK; ++m) {
      bool keep = mm[m] > 0;
      u32 kk = fkey(keep ? vv[m] : 100000.0f);
      // keep-bit at 16 + index: reproduces stable argsort for tied keys
      u32 pl = (u32)(gbase + m) | (keep ? 0x10000u : 0u);
      kv[m] = ((u64)kk << 32) | pl;
    }
  }

  // ---- bitonic stages k=2,4,8 entirely in registers ----
  // directions: up = ((global_i & k) == 0), global_i = gbase + m (gbase % 8 == 0)
  CE(0, 1, true) CE(2, 3, false) CE(4, 5, true) CE(6, 7, false)      // k=2
  CE(0, 2, true) CE(1, 3, true) CE(4, 6, false) CE(5, 7, false)      // k=4 j=2
  CE(0, 1, true) CE(2, 3, true) CE(4, 5, false) CE(6, 7, false)      // k=4 j=1
  {
    const bool u8 = (tid & 1) == 0;                                  // k=8
    CE(0, 4, u8) CE(1, 5, u8) CE(2, 6, u8) CE(3, 7, u8)
    CE(0, 2, u8) CE(1, 3, u8) CE(4, 6, u8) CE(5, 7, u8)
    CE(0, 1, u8) CE(2, 3, u8) CE(4, 5, u8) CE(6, 7, u8)
  }

  // ---- stages k=16..2048: j>=8 via LDS, j=4,2,1 in registers ----
  for (int k = 16; k <= N; k <<= 1) {
#pragma unroll
    for (int m = 0; m < EPK; m += 2) {            // regs -> LDS (b128, swizzled)
      int s = sw(gbase + m);
      *(ulonglong2*)(arr + s) = make_ulonglong2(kv[m], kv[m + 1]);
    }
    __syncthreads();
    for (int j = k >> 1; j >= 8; j >>= 1) {
      const int sj = sw(j);
#pragma unroll
      for (int it = 0; it < N / 2 / NT; ++it) {
        int t = tid + NT * it;
        int i = ((t & ~(j - 1)) << 1) | (t & (j - 1));
        int si = sw(i);
        int sx = si ^ sj;                          // sw(i|j), linearity
        u64 x = arr[si], y = arr[sx];
        bool up = (i & k) == 0;
        u64 mn = x < y ? x : y;
        u64 mx = x < y ? y : x;
        arr[si] = up ? mn : mx;
        arr[sx] = up ? mx : mn;
      }
      __syncthreads();
    }
#pragma unroll
    for (int m = 0; m < EPK; m += 2) {            // LDS -> regs (own slots only)
      int s = sw(gbase + m);
      ulonglong2 v = *(ulonglong2*)(arr + s);
      kv[m] = v.x; kv[m + 1] = v.y;
    }
    const bool uk = (gbase & k) == 0;             // uniform per thread for k>=16
    CE(0, 4, uk) CE(1, 5, uk) CE(2, 6, uk) CE(3, 7, uk)
    CE(0, 2, uk) CE(1, 3, uk) CE(4, 6, uk) CE(5, 7, uk)
    CE(0, 1, uk) CE(2, 3, uk) CE(4, 5, uk) CE(6, 7, uk)
  }
  // kv[] now holds sorted ranks [gbase, gbase+8); payloads in low words

  u32 pl[EPK];
#pragma unroll
  for (int m = 0; m < EPK; ++m) pl[m] = (u32)kv[m];

  // ---- channel phase: arr reused as 2 staged input1 rows ----
  float* rows = (float*)arr;
  const int lane = tid & 63;
  const int wv = tid >> 6;
  const int b = p >> 5, h = p & 31;

  for (int c0 = 0; c0 < 4; c0 += 2) {
    __syncthreads();   // prior readers of arr/rows are done
#pragma unroll
    for (int cc = 0; cc < 2; ++cc) {
      const float* r1 = input1 + ((long long)(((b * 4) + c0 + cc) * 32 + h)) * N;
#pragma unroll
      for (int q = 0; q < 2; ++q) {
        int i4 = tid + NT * q;
        ((float4*)(rows + cc * N))[i4] = ((const float4*)r1)[i4];  // coalesced
      }
    }
    __syncthreads();
#pragma unroll
    for (int cc = 0; cc < 2; ++cc) {
      const float* row = rows + cc * N;
      float e[EPK];
      float lsum = 0.f;
#pragma unroll
      for (int m = 0; m < EPK; ++m) {
        u32 q = pl[m];
        float v = row[q & 0xFFFFu];                 // gather by sorted index
        float pe = (q & 0x10000u) ? __expf(v) : 0.f;
        e[m] = pe;
        lsum += pe;
      }
      // block exclusive scan of per-thread sums (thread order == rank order)
      float inc = lsum;
#pragma unroll
      for (int d = 1; d < 64; d <<= 1) {
        float o = __shfl_up(inc, d, 64);
        if (lane >= d) inc += o;
      }
      if (lane == 63) wscan[wv] = inc;
      __syncthreads();
      float woff = 0.f;
      for (int w = 0; w < wv; ++w) woff += wscan[w];
      float excl = woff + inc - lsum;

      float prod = 1.f;
      float cum = excl;
#pragma unroll
      for (int m = 0; m < EPK; ++m) {
        cum += e[m];
        if (pl[m] & 0x10000u) prod *= (e[m] + 1e-9f) / (cum + 1e-9f);
      }
#pragma unroll
      for (int d = 32; d >= 1; d >>= 1) prod *= __shfl_xor(prod, d, 64);
      if (lane == 0) wprod[wv] = prod;
      __syncthreads();
      if (tid == 0) out[p * 4 + (c0 + cc)] = wprod[0] * wprod[1] * wprod[2] * wprod[3];
    }
  }
}

extern "C" void kernel_launch(void* const* d_in, const int* in_sizes, int n_in,
                              void* d_out, int out_size, void* d_ws, size_t ws_size,
                              hipStream_t stream) {
  const float* input1 = (const float*)d_in[0];
  // d_in[1] = mask1 — unused by the reference forward
  const float* input2 = (const float*)d_in[2];
  const int* mask2 = (const int*)d_in[3];
  float* out = (float*)d_out;

  const int problems = 128 * 32;  // bs * nh
  listmle_kernel<<<problems, NT, 0, stream>>>(input1, input2, mask2, out);
}

// Round 3
// 129.323 us; speedup vs baseline: 1.6539x; 1.1032x over previous
//
#include <hip/hip_runtime.h>

#define N   2048
#define NT  256
#define EPK 8   // elements per thread (N/NT)

typedef unsigned long long u64;
typedef unsigned int u32;

// monotone float->uint key: ascending uint order == ascending float order
__device__ __forceinline__ u32 fkey(float f) {
  u32 u = __float_as_uint(f);
  return (u & 0x80000000u) ? ~u : (u | 0x80000000u);
}

// XOR-linear bijective LDS slot swizzle (same as R1; kills roundtrip/exchange
// conflicts; linear over GF(2) so sw(a^b)=sw(a)^sw(b), bit0 untouched so u64
// pairs stay contiguous + 16B aligned for b128)
__device__ __forceinline__ int sw(int e) {
  return e ^ ((e >> 3) & 0xE) ^ ((e >> 1) & 8);
}

#define CE(x, y, up)                                  \
  {                                                   \
    if ((kv[x] > kv[y]) == (up)) {                    \
      u64 t_ = kv[x]; kv[x] = kv[y]; kv[y] = t_;      \
    }                                                 \
  }

// bitonic pass at element distance j = DIST*8: partner is lane^DIST, same
// register slot. Wave-synchronous: no barrier, no LDS storage.
template <int DIST>
__device__ __forceinline__ void shfl_pass(u64 kv[EPK], bool keep_min) {
#pragma unroll
  for (int m = 0; m < EPK; ++m) {
    u64 o = __shfl_xor(kv[m], DIST, 64);
    bool lt = kv[m] < o;
    u64 sel_min = lt ? kv[m] : o;
    u64 sel_max = lt ? o : kv[m];
    kv[m] = keep_min ? sel_min : sel_max;
  }
}

// register tail of stage k: j=4,2,1 within the thread's 8 elements
#define REG_TAIL(k)                                   \
  {                                                   \
    const bool uk = (gbase & (k)) == 0;               \
    CE(0, 4, uk) CE(1, 5, uk) CE(2, 6, uk) CE(3, 7, uk) \
    CE(0, 2, uk) CE(1, 3, uk) CE(4, 6, uk) CE(5, 7, uk) \
    CE(0, 1, uk) CE(2, 3, uk) CE(4, 5, uk) CE(6, 7, uk) \
  }

// shuffle pass for stage k, distance j (both compile-time)
#define SH(k, j) \
  shfl_pass<(j) / 8>(kv, ((gbase & (j)) == 0) == ((gbase & (k)) == 0));

__global__ __launch_bounds__(NT, 6) void listmle_kernel(
    const float* __restrict__ input1,
    const float* __restrict__ input2,
    const int* __restrict__ mask2,
    float* __restrict__ out) {
  __shared__ __align__(16) u64 arr[N];  // 16 KB; exchange buffer, then 2 staged rows
  __shared__ float wscan[NT / 64];
  __shared__ float wprod[NT / 64];

  const int p = blockIdx.x;      // p = b*32 + h
  const int tid = threadIdx.x;
  const int gbase = tid * EPK;   // this thread's 8 consecutive element slots
  const long long base2 = (long long)p * N;

  // ---- load 8 consecutive elements, build sort items ----
  const float4* i2v = (const float4*)(input2 + base2);
  const int4* m2v = (const int4*)(mask2 + base2);
  float4 va = i2v[2 * tid], vb = i2v[2 * tid + 1];
  int4 ma = m2v[2 * tid], mb = m2v[2 * tid + 1];

  u64 kv[EPK];
  {
    float vv[EPK] = {va.x, va.y, va.z, va.w, vb.x, vb.y, vb.z, vb.w};
    int mm[EPK] = {ma.x, ma.y, ma.z, ma.w, mb.x, mb.y, mb.z, mb.w};
#pragma unroll
    for (int m = 0; m < EPK; ++m) {
      bool keep = mm[m] > 0;
      u32 kk = fkey(keep ? vv[m] : 100000.0f);
      // keep-bit at 16 + index: reproduces stable argsort for tied keys
      u32 pl = (u32)(gbase + m) | (keep ? 0x10000u : 0u);
      kv[m] = ((u64)kk << 32) | pl;
    }
  }

  // cross-wave block exchange through LDS at element distance jx (>=512):
  // partner thread = tid ^ (jx/8), full 8-element block, same m slots.
  auto lds_exchange = [&](int jx, bool keep_min) {
#pragma unroll
    for (int m = 0; m < EPK; m += 2) {
      int s = sw(gbase + m);
      *(ulonglong2*)(arr + s) = make_ulonglong2(kv[m], kv[m + 1]);
    }
    __syncthreads();
    const int pb = gbase ^ jx;
#pragma unroll
    for (int m = 0; m < EPK; m += 2) {
      int s = sw(pb + m);
      ulonglong2 v = *(ulonglong2*)(arr + s);
      kv[m]     = ((kv[m]     < v.x) == keep_min) ? kv[m]     : v.x;
      kv[m + 1] = ((kv[m + 1] < v.y) == keep_min) ? kv[m + 1] : v.y;
    }
    __syncthreads();
  };

  // ---- bitonic stages k=2,4,8 entirely in registers ----
  CE(0, 1, true) CE(2, 3, false) CE(4, 5, true) CE(6, 7, false)   // k=2
  CE(0, 2, true) CE(1, 3, true) CE(4, 6, false) CE(5, 7, false)   // k=4 j=2
  CE(0, 1, true) CE(2, 3, true) CE(4, 5, false) CE(6, 7, false)   // k=4 j=1
  {
    const bool u8 = (tid & 1) == 0;                               // k=8
    CE(0, 4, u8) CE(1, 5, u8) CE(2, 6, u8) CE(3, 7, u8)
    CE(0, 2, u8) CE(1, 3, u8) CE(4, 6, u8) CE(5, 7, u8)
    CE(0, 1, u8) CE(2, 3, u8) CE(4, 5, u8) CE(6, 7, u8)
  }

  // ---- stages k=16..512: shuffles only, zero barriers ----
  SH(16, 8)  REG_TAIL(16)
  SH(32, 16) SH(32, 8) REG_TAIL(32)
  SH(64, 32) SH(64, 16) SH(64, 8) REG_TAIL(64)
  SH(128, 64) SH(128, 32) SH(128, 16) SH(128, 8) REG_TAIL(128)
  SH(256, 128) SH(256, 64) SH(256, 32) SH(256, 16) SH(256, 8) REG_TAIL(256)
  SH(512, 256) SH(512, 128) SH(512, 64) SH(512, 32) SH(512, 16) SH(512, 8)
  REG_TAIL(512)

  // ---- k=1024: one cross-wave exchange, then shuffles ----
  lds_exchange(512, ((gbase & 512) == 0) == ((gbase & 1024) == 0));
  SH(1024, 256) SH(1024, 128) SH(1024, 64) SH(1024, 32) SH(1024, 16)
  SH(1024, 8) REG_TAIL(1024)

  // ---- k=2048 (final full ascending merge, up always true) ----
  lds_exchange(1024, (gbase & 1024) == 0);
  lds_exchange(512, (gbase & 512) == 0);
  SH(2048, 256) SH(2048, 128) SH(2048, 64) SH(2048, 32) SH(2048, 16)
  SH(2048, 8) REG_TAIL(2048)
  // kv[] now holds sorted ranks [gbase, gbase+8); payloads in low words

  u32 pl[EPK];
#pragma unroll
  for (int m = 0; m < EPK; ++m) pl[m] = (u32)kv[m];

  // ---- channel phase: arr reused as 2 staged input1 rows ----
  float* rows = (float*)arr;
  const int lane = tid & 63;
  const int wv = tid >> 6;
  const int b = p >> 5, h = p & 31;

  for (int c0 = 0; c0 < 4; c0 += 2) {
    __syncthreads();  // prior readers of arr/rows are done
#pragma unroll
    for (int cc = 0; cc < 2; ++cc) {
      const float* r1 = input1 + ((long long)(((b * 4) + c0 + cc) * 32 + h)) * N;
#pragma unroll
      for (int q = 0; q < 2; ++q) {
        int i4 = tid + NT * q;
        ((float4*)(rows + cc * N))[i4] = ((const float4*)r1)[i4];  // coalesced
      }
    }
    __syncthreads();
#pragma unroll
    for (int cc = 0; cc < 2; ++cc) {
      const float* row = rows + cc * N;
      float e[EPK];
      float lsum = 0.f;
#pragma unroll
      for (int m = 0; m < EPK; ++m) {
        u32 q = pl[m];
        float v = row[q & 0xFFFFu];                // gather by sorted index
        float pe = (q & 0x10000u) ? __expf(v) : 0.f;
        e[m] = pe;
        lsum += pe;
      }
      // block exclusive scan of per-thread sums (thread order == rank order)
      float inc = lsum;
#pragma unroll
      for (int d = 1; d < 64; d <<= 1) {
        float o = __shfl_up(inc, d, 64);
        if (lane >= d) inc += o;
      }
      if (lane == 63) wscan[wv] = inc;
      __syncthreads();
      float woff = 0.f;
      for (int w = 0; w < wv; ++w) woff += wscan[w];
      float excl = woff + inc - lsum;

      float prod = 1.f;
      float cum = excl;
#pragma unroll
      for (int m = 0; m < EPK; ++m) {
        cum += e[m];
        if (pl[m] & 0x10000u) prod *= (e[m] + 1e-9f) / (cum + 1e-9f);
      }
#pragma unroll
      for (int d = 32; d >= 1; d >>= 1) prod *= __shfl_xor(prod, d, 64);
      if (lane == 0) wprod[wv] = prod;
      __syncthreads();
      if (tid == 0) out[p * 4 + (c0 + cc)] = wprod[0] * wprod[1] * wprod[2] * wprod[3];
    }
  }
}

extern "C" void kernel_launch(void* const* d_in, const int* in_sizes, int n_in,
                              void* d_out, int out_size, void* d_ws, size_t ws_size,
                              hipStream_t stream) {
  const float* input1 = (const float*)d_in[0];
  // d_in[1] = mask1 — unused by the reference forward
  const float* input2 = (const float*)d_in[2];
  const int* mask2 = (const int*)d_in[3];
  float* out = (float*)d_out;

  const int problems = 128 * 32;  // bs * nh
  listmle_kernel<<<problems, NT, 0, stream>>>(input1, input2, mask2, out);
}